// Round 1
// baseline (433.238 us; speedup 1.0000x reference)
//
#include <hip/hip_runtime.h>
#include <cstdint>
#include <cstddef>

typedef __bf16 bf16_t;
typedef __bf16 bf16x8 __attribute__((ext_vector_type(8)));
typedef float  f32x4  __attribute__((ext_vector_type(4)));

#define DHW   25088
#define SCALE 0.17677669529663687f  /* 32^-0.5 */

__device__ inline f32x4 mfma16(bf16x8 a, bf16x8 b, f32x4 c) {
  return __builtin_amdgcn_mfma_f32_16x16x32_bf16(a, b, c, 0, 0, 0);
}

// window-order row -> global (rolled) token row
__device__ inline size_t wrow_to_grow(int orow) {
  int win = orow / 98, tok = orow % 98;
  int b = win >> 8, wr = win & 255;
  int bd = wr >> 6, bh = (wr >> 3) & 7, bwi = wr & 7;
  int md = tok / 49, mh = (tok / 7) % 7, mw = tok % 7;
  int d = (bd * 2 + md + 1) & 7;
  int h = bh * 7 + mh + 3; if (h >= 56) h -= 56;
  int w = bwi * 7 + mw + 3; if (w >= 56) w -= 56;
  return (size_t)b * DHW + (size_t)((d * 56 + h) * 56 + w);
}

// ---------------- K0a: weight cast ----------------
__global__ __launch_bounds__(256) void prep_kernel(
    const float* __restrict__ qkv_w, const float* __restrict__ proj_w,
    const float* __restrict__ fc1_w,
    bf16_t* __restrict__ wq, bf16_t* __restrict__ wp, bf16_t* __restrict__ wf)
{
  int idx = blockIdx.x * 256 + threadIdx.x;
  if (idx < 110592) { wq[idx] = (bf16_t)qkv_w[idx]; return; }
  idx -= 110592;
  if (idx < 36864) { wp[idx] = (bf16_t)proj_w[idx]; return; }
  idx -= 36864;
  if (idx < 36864) { wf[idx] = (bf16_t)fc1_w[idx]; }
}

// ---------------- K0b: bias+mask table, 8 window-types, MFMA C-layout -
// bmr[type(8)][h(6)][mt(7)][lane(64)][e(32)], e = nt2*4 + v; pad entries -1e30.
__global__ __launch_bounds__(256) void prep_bm_kernel(
    const float* __restrict__ rel_bias, const float* __restrict__ mask,
    bf16_t* __restrict__ bmr)
{
  int idx = blockIdx.x * 256 + threadIdx.x;   // exactly 688,128 threads
  int e    = idx & 31;
  int lane = (idx >> 5) & 63;
  int t2   = idx >> 11;
  int mt   = t2 % 7;
  int wh   = t2 / 7;
  int type = wh / 6, h = wh - type * 6;
  int winb = ((type & 4) ? 3 : 0) * 64 + ((type & 2) ? 7 : 0) * 8 + ((type & 1) ? 7 : 0);
  int g = lane >> 4, li = lane & 15;
  int nt2 = e >> 2, v = e & 3;
  int row = mt * 16 + g * 4 + v;
  int col = nt2 * 16 + li;
  float val = -1e30f;
  if (row < 98 && col < 98 && nt2 < 7) {
    int di = row / 49 - col / 49 + 1;
    int hi = (row / 7) % 7 - (col / 7) % 7 + 6;
    int wi = row % 7 - col % 7 + 6;
    int rid = di * 169 + hi * 13 + wi;
    val = mask[winb * 9604 + row * 98 + col] + rel_bias[rid * 6 + h];
  }
  bmr[idx] = (bf16_t)val;
}

// ---------------- K1: fully fused per-window block ----------------
// One block = one window (98 tokens). 7 waves, each owns a 16-row stripe.
// LN (A-frags in regs) -> QKV GEMM -> attention (6 heads) -> proj -> fc1.
// LDS overlays: U: wq/wp/wf staging <-> P;  Qs: Q -> attn-out;  Ks: K -> C1.
__global__ __launch_bounds__(448, 2) void fused_kernel(
    const float* __restrict__ x, const float* __restrict__ gw,
    const float* __restrict__ bw_, const bf16_t* __restrict__ wq,
    const float* __restrict__ qkv_b, const bf16_t* __restrict__ wp,
    const float* __restrict__ proj_b, const bf16_t* __restrict__ wf,
    const float* __restrict__ fc1_b, const bf16_t* __restrict__ bmr,
    float* __restrict__ out)
{
  __shared__ __align__(16) char smem[163392];
  bf16_t* U  = (bf16_t*)smem;                    // Bs 64x200 (25.6K) | PS 112x136 (30.4K)
  bf16_t* Qs = (bf16_t*)(smem + 30464);          // 98x200: Q (scaled) -> attn out
  bf16_t* Ks = (bf16_t*)(smem + 69664);          // 98x200: K -> C1 (proj out)
  bf16_t* Vt = (bf16_t*)(smem + 108864);         // 192x136: V transposed [d][tok]
  float*  qb = (float*)(smem + 161088);          // 576 f32 qkv bias; later 192 f32 pb/fb
  float* gwb = (float*)smem;                     // LN gamma/beta overlay on U

  #define BS(r, c)  U[(r) * 200 + (c)]
  #define PSd(r, c) U[(r) * 136 + (c)]
  #define QS(r, c)  Qs[(r) * 200 + (c)]
  #define KS(r, c)  Ks[(r) * 200 + (c)]
  #define VT(d, t)  Vt[(d) * 136 + (t)]

  int win  = blockIdx.x;
  int winb = win & 255;
  int type = (((winb >> 6) == 3) ? 4 : 0) | ((((winb >> 3) & 7) == 7) ? 2 : 0)
           | (((winb & 7) == 7) ? 1 : 0);
  int tid  = threadIdx.x;
  int wid  = tid >> 6, lane = tid & 63;
  int g = lane >> 4, li = lane & 15;

  // small tables + V token-pad zero (cols 96..127; 96,97 overwritten by real V)
  if (tid < 192) { gwb[tid] = gw[tid]; gwb[192 + tid] = bw_[tid]; }
  for (int c = tid; c < 576; c += 448) qb[c] = qkv_b[c];
  {
    uint4 z = {0u, 0u, 0u, 0u};
    for (int c = tid; c < 768; c += 448) {
      int d = c >> 2, part = c & 3;
      *(uint4*)&VT(d, 96 + part * 8) = z;
    }
  }

  // ---- LN -> A fragments directly in registers ----
  // lane (wid,l) owns row wid*16+(l&15), k-cols { ks*32 + g*8 + j } (= A-frag layout)
  int r = wid * 16 + li;
  float v[48];
  if (r < 98) {
    size_t growr = wrow_to_grow(win * 98 + r);
    const float* xr = x + growr * 192 + g * 8;
    #pragma unroll
    for (int ks = 0; ks < 6; ks++) {
      *(float4*)&v[ks * 8]     = *(const float4*)(xr + ks * 32);
      *(float4*)&v[ks * 8 + 4] = *(const float4*)(xr + ks * 32 + 4);
    }
  } else {
    #pragma unroll
    for (int i = 0; i < 48; i++) v[i] = 0.f;
  }
  float s = 0.f, sq = 0.f;
  #pragma unroll
  for (int i = 0; i < 48; i++) { s += v[i]; sq += v[i] * v[i]; }
  s += __shfl_xor(s, 16, 64); sq += __shfl_xor(sq, 16, 64);
  s += __shfl_xor(s, 32, 64); sq += __shfl_xor(sq, 32, 64);
  float mu   = s * (1.0f / 192.0f);
  float var  = sq * (1.0f / 192.0f) - mu * mu;
  float rstd = rsqrtf(var + 1e-5f);
  __syncthreads();                       // gwb staged (readers below, freed at nt=0 barrier)
  bf16x8 afr[6];
  #pragma unroll
  for (int ks = 0; ks < 6; ks++) {
    bf16x8 t;
    #pragma unroll
    for (int j = 0; j < 8; j++) {
      int c = ks * 32 + g * 8 + j;
      t[j] = (r < 98) ? (bf16_t)((v[ks * 8 + j] - mu) * rstd * gwb[c] + gwb[192 + c])
                      : (bf16_t)0.0f;
    }
    afr[ks] = t;
  }

  // ---- QKV GEMM: [112x192] @ wq^T -> Qs (scaled) / Ks / Vt ----
  uint4 st[4];
  #pragma unroll
  for (int i = 0; i < 4; i++) {
    int c = tid + 448 * i;
    if (i < 3 || c < 1536) {
      int rr = c / 24, ck = c % 24;
      st[i] = *(const uint4*)(wq + (size_t)rr * 192 + ck * 8);
    }
  }
  for (int nt = 0; nt < 9; nt++) {
    __syncthreads();                     // prev tile readers done (nt=0: gwb dead)
    #pragma unroll
    for (int i = 0; i < 4; i++) {
      int c = tid + 448 * i;
      if (i < 3 || c < 1536) {
        int rr = c / 24, ck = c % 24;
        *(uint4*)&BS(rr, ck * 8) = st[i];
      }
    }
    __syncthreads();
    if (nt < 8) {
      #pragma unroll
      for (int i = 0; i < 4; i++) {
        int c = tid + 448 * i;
        if (i < 3 || c < 1536) {
          int rr = c / 24, ck = c % 24;
          st[i] = *(const uint4*)(wq + (size_t)(nt + 1) * 12288 + (size_t)rr * 192 + ck * 8);
        }
      }
    }
    f32x4 acc[4] = {};
    #pragma unroll
    for (int ks = 0; ks < 6; ks++) {
      bf16x8 a = afr[ks];
      #pragma unroll
      for (int ni = 0; ni < 4; ni++) {
        bf16x8 b = *(const bf16x8*)&BS(ni * 16 + li, ks * 32 + g * 8);
        acc[ni] = mfma16(a, b, acc[ni]);
      }
    }
    #pragma unroll
    for (int ni = 0; ni < 4; ni++)
    #pragma unroll
    for (int vv = 0; vv < 4; vv++) {
      int row = wid * 16 + g * 4 + vv;
      if (row < 98) {
        int col = nt * 64 + ni * 16 + li;
        float val = acc[ni][vv] + qb[col];
        if (nt < 3)      QS(row, col)       = (bf16_t)(val * SCALE);
        else if (nt < 6) KS(row, col - 192) = (bf16_t)val;
        else             VT(col - 384, row) = (bf16_t)val;
      }
    }
  }
  __syncthreads();                       // Q/K/V staged; U: Bs -> PS

  // ---- attention: wave = m-tile (mt = wid), loop 6 heads ----
  int mt  = wid;
  int rq  = mt * 16 + li;
  int rqc = rq < 98 ? rq : 97;           // pad lanes read a real row; bm masks pads
  for (int h = 0; h < 6; h++) {
    const bf16_t* bmp = bmr + ((((size_t)(type * 6 + h)) * 7 + mt) * 64 + lane) * 32;
    bf16x8 bm0 = *(const bf16x8*)(bmp);
    bf16x8 bm1 = *(const bf16x8*)(bmp + 8);
    bf16x8 bm2 = *(const bf16x8*)(bmp + 16);
    bf16x8 bm3 = *(const bf16x8*)(bmp + 24);
    bf16x8 af = *(const bf16x8*)&QS(rqc, h * 32 + g * 8);
    float logit[7][4];
    #pragma unroll
    for (int nt2 = 0; nt2 < 7; nt2++) {
      int rk = nt2 * 16 + li;
      int rkc = rk < 98 ? rk : 97;
      bf16x8 bfr = *(const bf16x8*)&KS(rkc, h * 32 + g * 8);
      f32x4 z = {};
      f32x4 S = mfma16(af, bfr, z);
      #pragma unroll
      for (int vv = 0; vv < 4; vv++) {
        int e = nt2 * 4 + vv;
        float bmv = (e < 8) ? (float)bm0[e] : (e < 16) ? (float)bm1[e - 8]
                  : (e < 24) ? (float)bm2[e - 16] : (float)bm3[e - 24];
        logit[nt2][vv] = S[vv] + bmv;    // Q pre-scaled
      }
    }
    #pragma unroll
    for (int vv = 0; vv < 4; vv++) {
      float mx = logit[0][vv];
      #pragma unroll
      for (int nt2 = 1; nt2 < 7; nt2++) mx = fmaxf(mx, logit[nt2][vv]);
      #pragma unroll
      for (int off = 1; off < 16; off <<= 1) mx = fmaxf(mx, __shfl_xor(mx, off, 64));
      float se = 0.f;
      #pragma unroll
      for (int nt2 = 0; nt2 < 7; nt2++) {
        float p = __expf(logit[nt2][vv] - mx);
        logit[nt2][vv] = p; se += p;
      }
      #pragma unroll
      for (int off = 1; off < 16; off <<= 1) se += __shfl_xor(se, off, 64);
      float inv = 1.0f / se;
      int row = mt * 16 + g * 4 + vv;
      #pragma unroll
      for (int nt2 = 0; nt2 < 7; nt2++)
        PSd(row, nt2 * 16 + li) = (bf16_t)(logit[nt2][vv] * inv);
      PSd(row, 112 + li) = (bf16_t)0.0f;
    }
    // PV (wave-local P round trip; no barrier needed)
    f32x4 o0 = {}, o1 = {};
    #pragma unroll
    for (int ks = 0; ks < 4; ks++) {
      int ko = ks * 32 + g * 8;
      bf16x8 pf = *(const bf16x8*)&PSd(mt * 16 + li, ko);
      bf16x8 v0 = *(const bf16x8*)&VT(h * 32 + li, ko);
      bf16x8 v1 = *(const bf16x8*)&VT(h * 32 + 16 + li, ko);
      o0 = mfma16(pf, v0, o0);
      o1 = mfma16(pf, v1, o1);
    }
    // head output overwrites Q's (already-consumed) head-h columns
    #pragma unroll
    for (int vv = 0; vv < 4; vv++) {
      int row = mt * 16 + g * 4 + vv;
      if (row < 98) {
        QS(row, h * 32 + li)      = (bf16_t)o0[vv];
        QS(row, h * 32 + 16 + li) = (bf16_t)o1[vv];
      }
    }
  }

  // ---- proj GEMM: C1 = Ao @ wp^T + pb -> Ks overlay ----
  float* bfb = qb;                        // qkv bias dead -> pb/fb overlay
  if (tid < 192) bfb[tid] = proj_b[tid];
  bf16x8 a2[6];
  #pragma unroll
  for (int ks = 0; ks < 6; ks++)
    a2[ks] = *(const bf16x8*)&QS(rqc, ks * 32 + g * 8);
  #pragma unroll
  for (int i = 0; i < 4; i++) {
    int c = tid + 448 * i;
    if (i < 3 || c < 1536) {
      int rr = c / 24, ck = c % 24;
      st[i] = *(const uint4*)(wp + (size_t)rr * 192 + ck * 8);
    }
  }
  for (int nt = 0; nt < 3; nt++) {
    __syncthreads();                      // nt=0: all PV reads of PS done
    #pragma unroll
    for (int i = 0; i < 4; i++) {
      int c = tid + 448 * i;
      if (i < 3 || c < 1536) {
        int rr = c / 24, ck = c % 24;
        *(uint4*)&BS(rr, ck * 8) = st[i];
      }
    }
    __syncthreads();
    if (nt < 2) {
      #pragma unroll
      for (int i = 0; i < 4; i++) {
        int c = tid + 448 * i;
        if (i < 3 || c < 1536) {
          int rr = c / 24, ck = c % 24;
          st[i] = *(const uint4*)(wp + (size_t)(nt + 1) * 12288 + (size_t)rr * 192 + ck * 8);
        }
      }
    }
    f32x4 acc[4] = {};
    #pragma unroll
    for (int ks = 0; ks < 6; ks++) {
      bf16x8 a = a2[ks];
      #pragma unroll
      for (int ni = 0; ni < 4; ni++) {
        bf16x8 b = *(const bf16x8*)&BS(ni * 16 + li, ks * 32 + g * 8);
        acc[ni] = mfma16(a, b, acc[ni]);
      }
    }
    #pragma unroll
    for (int ni = 0; ni < 4; ni++)
    #pragma unroll
    for (int vv = 0; vv < 4; vv++) {
      int row = wid * 16 + g * 4 + vv;
      if (row < 98) {
        int col = nt * 64 + ni * 16 + li;
        KS(row, col) = (bf16_t)(acc[ni][vv] + bfb[col]);
      }
    }
  }

  // ---- fc1 GEMM + GELU + residual ----
  bf16x8 a3[6];
  #pragma unroll
  for (int ks = 0; ks < 6; ks++)
    a3[ks] = *(const bf16x8*)&KS(rqc, ks * 32 + g * 8);
  #pragma unroll
  for (int i = 0; i < 4; i++) {
    int c = tid + 448 * i;
    if (i < 3 || c < 1536) {
      int rr = c / 24, ck = c % 24;
      st[i] = *(const uint4*)(wf + (size_t)rr * 192 + ck * 8);
    }
  }
  size_t growv[4];
  #pragma unroll
  for (int vv = 0; vv < 4; vv++) {
    int row = wid * 16 + g * 4 + vv;
    growv[vv] = (row < 98) ? wrow_to_grow(win * 98 + row) : (size_t)0;
  }
  for (int nt = 0; nt < 3; nt++) {
    __syncthreads();                      // nt=0: all proj reads of Bs/bfb done
    #pragma unroll
    for (int i = 0; i < 4; i++) {
      int c = tid + 448 * i;
      if (i < 3 || c < 1536) {
        int rr = c / 24, ck = c % 24;
        *(uint4*)&BS(rr, ck * 8) = st[i];
      }
    }
    if (nt == 0 && tid < 192) bfb[tid] = fc1_b[tid];
    __syncthreads();
    if (nt < 2) {
      #pragma unroll
      for (int i = 0; i < 4; i++) {
        int c = tid + 448 * i;
        if (i < 3 || c < 1536) {
          int rr = c / 24, ck = c % 24;
          st[i] = *(const uint4*)(wf + (size_t)(nt + 1) * 12288 + (size_t)rr * 192 + ck * 8);
        }
      }
    }
    f32x4 acc[4] = {};
    #pragma unroll
    for (int ks = 0; ks < 6; ks++) {
      bf16x8 a = a3[ks];
      #pragma unroll
      for (int ni = 0; ni < 4; ni++) {
        bf16x8 b = *(const bf16x8*)&BS(ni * 16 + li, ks * 32 + g * 8);
        acc[ni] = mfma16(a, b, acc[ni]);
      }
    }
    #pragma unroll
    for (int vv = 0; vv < 4; vv++) {
      int row = wid * 16 + g * 4 + vv;
      if (row < 98) {
        const float* xr = x + growv[vv] * 192;
        float* op = out + growv[vv] * 192;
        #pragma unroll
        for (int ni = 0; ni < 4; ni++) {
          int col = nt * 64 + ni * 16 + li;
          float val = acc[ni][vv] + bfb[col];
          float ge = 0.5f * val * (1.0f + erff(val * 0.70710678118654752f));
          op[col] = xr[col] + ge;
        }
      }
    }
  }
  #undef BS
  #undef PSd
  #undef QS
  #undef KS
  #undef VT
}

// ---------------- launch ----------------
extern "C" void kernel_launch(void* const* d_in, const int* in_sizes, int n_in,
                              void* d_out, int out_size, void* d_ws, size_t ws_size,
                              hipStream_t stream) {
  (void)in_sizes; (void)n_in; (void)out_size; (void)ws_size;
  const float* x         = (const float*)d_in[0];
  const float* attn_mask = (const float*)d_in[1];
  const float* n1g       = (const float*)d_in[2];
  const float* n1b       = (const float*)d_in[3];
  const float* qkv_w     = (const float*)d_in[4];
  const float* qkv_b     = (const float*)d_in[5];
  const float* rel_bias  = (const float*)d_in[6];
  const float* proj_w    = (const float*)d_in[7];
  const float* proj_b    = (const float*)d_in[8];
  const float* fc1_w     = (const float*)d_in[9];
  const float* fc1_b     = (const float*)d_in[10];
  float* out = (float*)d_out;

  char* ws = (char*)d_ws;
  size_t off = 0;
  auto alloc = [&](size_t bytes) -> char* {
    char* p = ws + off;
    off += (bytes + 255) & ~(size_t)255;
    return p;
  };
  bf16_t* wq  = (bf16_t*)alloc(110592 * 2);
  bf16_t* wp  = (bf16_t*)alloc(36864 * 2);
  bf16_t* wf  = (bf16_t*)alloc(36864 * 2);
  bf16_t* bmr = (bf16_t*)alloc((size_t)688128 * 2);

  prep_kernel<<<720, 256, 0, stream>>>(qkv_w, proj_w, fc1_w, wq, wp, wf);
  prep_bm_kernel<<<2688, 256, 0, stream>>>(rel_bias, attn_mask, bmr);
  fused_kernel<<<1024, 448, 0, stream>>>(x, n1g, n1b, wq, qkv_b, wp, proj_b,
                                         wf, fc1_b, bmr, out);
}

// Round 2
// 386.975 us; speedup vs baseline: 1.1195x; 1.1195x over previous
//
#include <hip/hip_runtime.h>
#include <cstdint>
#include <cstddef>

typedef __bf16 bf16_t;
typedef __bf16 bf16x8 __attribute__((ext_vector_type(8)));
typedef float  f32x4  __attribute__((ext_vector_type(4)));

#define DHW   25088
#define SCALE 0.17677669529663687f  /* 32^-0.5 */

__device__ inline f32x4 mfma16(bf16x8 a, bf16x8 b, f32x4 c) {
  return __builtin_amdgcn_mfma_f32_16x16x32_bf16(a, b, c, 0, 0, 0);
}

// window-order row -> global (rolled) token row
__device__ inline size_t wrow_to_grow(int orow) {
  int win = orow / 98, tok = orow % 98;
  int b = win >> 8, wr = win & 255;
  int bd = wr >> 6, bh = (wr >> 3) & 7, bwi = wr & 7;
  int md = tok / 49, mh = (tok / 7) % 7, mw = tok % 7;
  int d = (bd * 2 + md + 1) & 7;
  int h = bh * 7 + mh + 3; if (h >= 56) h -= 56;
  int w = bwi * 7 + mw + 3; if (w >= 56) w -= 56;
  return (size_t)b * DHW + (size_t)((d * 56 + h) * 56 + w);
}

// ---------------- K0: weight cast + bias/mask table (merged) ----------
// bmr[type(8)][h(6)][mt(7)][lane(64)][e(32)], e = nt2*4 + v; pad entries -1e30.
__global__ __launch_bounds__(256) void prep_all_kernel(
    const float* __restrict__ qkv_w, const float* __restrict__ proj_w,
    const float* __restrict__ fc1_w, const float* __restrict__ rel_bias,
    const float* __restrict__ mask,
    bf16_t* __restrict__ wq, bf16_t* __restrict__ wp, bf16_t* __restrict__ wf,
    bf16_t* __restrict__ bmr)
{
  int idx = blockIdx.x * 256 + threadIdx.x;
  if (idx < 110592) { wq[idx] = (bf16_t)qkv_w[idx]; return; }
  idx -= 110592;
  if (idx < 36864) { wp[idx] = (bf16_t)proj_w[idx]; return; }
  idx -= 36864;
  if (idx < 36864) { wf[idx] = (bf16_t)fc1_w[idx]; return; }
  idx -= 36864;
  if (idx >= 688128) return;
  int e    = idx & 31;
  int lane = (idx >> 5) & 63;
  int t2   = idx >> 11;
  int mt   = t2 % 7;
  int wh   = t2 / 7;
  int type = wh / 6, h = wh - type * 6;
  int winb = ((type & 4) ? 3 : 0) * 64 + ((type & 2) ? 7 : 0) * 8 + ((type & 1) ? 7 : 0);
  int g = lane >> 4, li = lane & 15;
  int nt2 = e >> 2, v = e & 3;
  int row = mt * 16 + g * 4 + v;
  int col = nt2 * 16 + li;
  float val = -1e30f;
  if (row < 98 && col < 98 && nt2 < 7) {
    int di = row / 49 - col / 49 + 1;
    int hi = (row / 7) % 7 - (col / 7) % 7 + 6;
    int wi = row % 7 - col % 7 + 6;
    int rid = di * 169 + hi * 13 + wi;
    val = mask[winb * 9604 + row * 98 + col] + rel_bias[rid * 6 + h];
  }
  bmr[idx] = (bf16_t)val;
}

// ---------------- K1: fully fused per-window block, 14 waves ----------
// wave = (wm, wn): wm = m-stripe (7), wn = N-half. QKV/proj/fc1 split the
// 4 ni-subtiles 2/2 across wn; attention splits 6 heads 3/3 across wn.
// P transpose goes through 14 wave-private 16x40 slots chunked over k
// (overlaid on the weight-staging buffer, wave-local, no barrier).
__global__ __launch_bounds__(896) void fused_kernel(
    const float* __restrict__ x, const float* __restrict__ gw,
    const float* __restrict__ bw_, const bf16_t* __restrict__ wq,
    const float* __restrict__ qkv_b, const bf16_t* __restrict__ wp,
    const float* __restrict__ proj_b, const bf16_t* __restrict__ wf,
    const float* __restrict__ fc1_b, const bf16_t* __restrict__ bmr,
    float* __restrict__ out)
{
  __shared__ __align__(16) char smem[158528];
  bf16_t* U  = (bf16_t*)smem;                    // 25600B: BS staging | P slots | gwb
  bf16_t* Qs = (bf16_t*)(smem + 25600);          // 39200: Q (scaled) -> attn out
  bf16_t* Ks = (bf16_t*)(smem + 64800);          // 39200: K -> C1 (proj out)
  bf16_t* Vt = (bf16_t*)(smem + 104000);         // 52224: V transposed [d][tok]
  float*  qb = (float*)(smem + 156224);          // 576 f32 qkv bias; later pb/fb
  float* gwb = (float*)smem;                     // LN gamma/beta overlay on U

  #define BS(r, c)     U[(r) * 200 + (c)]
  #define PSc(w, r, c) U[(w) * 640 + (r) * 40 + (c)]
  #define QS(r, c)     Qs[(r) * 200 + (c)]
  #define KS(r, c)     Ks[(r) * 200 + (c)]
  #define VT(d, t)     Vt[(d) * 136 + (t)]

  int win  = blockIdx.x;
  int winb = win & 255;
  int type = (((winb >> 6) == 3) ? 4 : 0) | ((((winb >> 3) & 7) == 7) ? 2 : 0)
           | (((winb & 7) == 7) ? 1 : 0);
  int tid  = threadIdx.x;
  int wid  = tid >> 6, lane = tid & 63;
  int wn = wid & 1, wm = wid >> 1;               // wm 0..6, wn 0..1
  int g = lane >> 4, li = lane & 15;

  // small tables + V token-pad zero (cols 96..127; 96,97 overwritten by real V)
  if (tid < 192) { gwb[tid] = gw[tid]; gwb[192 + tid] = bw_[tid]; }
  if (tid < 576) qb[tid] = qkv_b[tid];
  if (tid < 768) {
    uint4 z = {0u, 0u, 0u, 0u};
    int d = tid >> 2, part = tid & 3;
    *(uint4*)&VT(d, 96 + part * 8) = z;
  }

  // ---- LN -> A fragments directly in registers (duplicated per wn) ----
  int r = wm * 16 + li;
  float v[48];
  if (r < 98) {
    size_t growr = wrow_to_grow(win * 98 + r);
    const float* xr = x + growr * 192 + g * 8;
    #pragma unroll
    for (int ks = 0; ks < 6; ks++) {
      *(float4*)&v[ks * 8]     = *(const float4*)(xr + ks * 32);
      *(float4*)&v[ks * 8 + 4] = *(const float4*)(xr + ks * 32 + 4);
    }
  } else {
    #pragma unroll
    for (int i = 0; i < 48; i++) v[i] = 0.f;
  }
  float s = 0.f, sq = 0.f;
  #pragma unroll
  for (int i = 0; i < 48; i++) { s += v[i]; sq += v[i] * v[i]; }
  s += __shfl_xor(s, 16, 64); sq += __shfl_xor(sq, 16, 64);
  s += __shfl_xor(s, 32, 64); sq += __shfl_xor(sq, 32, 64);
  float mu   = s * (1.0f / 192.0f);
  float var  = sq * (1.0f / 192.0f) - mu * mu;
  float rstd = rsqrtf(var + 1e-5f);
  __syncthreads();                       // gwb/qb/VT-pad staged
  bf16x8 afr[6];
  #pragma unroll
  for (int ks = 0; ks < 6; ks++) {
    bf16x8 t;
    #pragma unroll
    for (int j = 0; j < 8; j++) {
      int c = ks * 32 + g * 8 + j;
      t[j] = (r < 98) ? (bf16_t)((v[ks * 8 + j] - mu) * rstd * gwb[c] + gwb[192 + c])
                      : (bf16_t)0.0f;
    }
    afr[ks] = t;
  }

  // ---- QKV GEMM: [112x192] @ wq^T -> Qs (scaled) / Ks / Vt ----
  uint4 st[2];
  #pragma unroll
  for (int i = 0; i < 2; i++) {
    int c = tid + 896 * i;
    if (c < 1536) {
      int rr = c / 24, ck = c % 24;
      st[i] = *(const uint4*)(wq + (size_t)rr * 192 + ck * 8);
    }
  }
  for (int nt = 0; nt < 9; nt++) {
    __syncthreads();                     // prev tile readers done (nt=0: gwb dead)
    #pragma unroll
    for (int i = 0; i < 2; i++) {
      int c = tid + 896 * i;
      if (c < 1536) {
        int rr = c / 24, ck = c % 24;
        *(uint4*)&BS(rr, ck * 8) = st[i];
      }
    }
    __syncthreads();
    if (nt < 8) {
      #pragma unroll
      for (int i = 0; i < 2; i++) {
        int c = tid + 896 * i;
        if (c < 1536) {
          int rr = c / 24, ck = c % 24;
          st[i] = *(const uint4*)(wq + (size_t)(nt + 1) * 12288 + (size_t)rr * 192 + ck * 8);
        }
      }
    }
    f32x4 acc[2] = {};
    #pragma unroll
    for (int ks = 0; ks < 6; ks++) {
      bf16x8 a = afr[ks];
      #pragma unroll
      for (int nl = 0; nl < 2; nl++) {
        bf16x8 b = *(const bf16x8*)&BS((wn * 2 + nl) * 16 + li, ks * 32 + g * 8);
        acc[nl] = mfma16(a, b, acc[nl]);
      }
    }
    #pragma unroll
    for (int nl = 0; nl < 2; nl++)
    #pragma unroll
    for (int vv = 0; vv < 4; vv++) {
      int row = wm * 16 + g * 4 + vv;
      if (row < 98) {
        int col = nt * 64 + (wn * 2 + nl) * 16 + li;
        float val = acc[nl][vv] + qb[col];
        if (nt < 3)      QS(row, col)       = (bf16_t)(val * SCALE);
        else if (nt < 6) KS(row, col - 192) = (bf16_t)val;
        else             VT(col - 384, row) = (bf16_t)val;
      }
    }
  }
  __syncthreads();                       // Q/K/V staged (cross-wave cols)

  // ---- attention: wave (wm, wn) -> m-stripe wm, heads wn*3..wn*3+2 ----
  int mt  = wm;
  int rq  = mt * 16 + li;
  int rqc = rq < 98 ? rq : 97;           // pad lanes read a real row; bm masks pads
  for (int hh = 0; hh < 3; hh++) {
    int h = wn * 3 + hh;
    const bf16_t* bmp = bmr + ((((size_t)(type * 6 + h)) * 7 + mt) * 64 + lane) * 32;
    bf16x8 bm0 = *(const bf16x8*)(bmp);
    bf16x8 bm1 = *(const bf16x8*)(bmp + 8);
    bf16x8 bm2 = *(const bf16x8*)(bmp + 16);
    bf16x8 bm3 = *(const bf16x8*)(bmp + 24);
    bf16x8 af = *(const bf16x8*)&QS(rqc, h * 32 + g * 8);
    float logit[7][4];
    #pragma unroll
    for (int nt2 = 0; nt2 < 7; nt2++) {
      int rk = nt2 * 16 + li;
      int rkc = rk < 98 ? rk : 97;
      bf16x8 bfr = *(const bf16x8*)&KS(rkc, h * 32 + g * 8);
      f32x4 z = {};
      f32x4 S = mfma16(af, bfr, z);
      #pragma unroll
      for (int vv = 0; vv < 4; vv++) {
        int e = nt2 * 4 + vv;
        float bmv = (e < 8) ? (float)bm0[e] : (e < 16) ? (float)bm1[e - 8]
                  : (e < 24) ? (float)bm2[e - 16] : (float)bm3[e - 24];
        logit[nt2][vv] = S[vv] + bmv;    // Q pre-scaled
      }
    }
    #pragma unroll
    for (int vv = 0; vv < 4; vv++) {
      float mx = logit[0][vv];
      #pragma unroll
      for (int nt2 = 1; nt2 < 7; nt2++) mx = fmaxf(mx, logit[nt2][vv]);
      #pragma unroll
      for (int off = 1; off < 16; off <<= 1) mx = fmaxf(mx, __shfl_xor(mx, off, 64));
      float se = 0.f;
      #pragma unroll
      for (int nt2 = 0; nt2 < 7; nt2++) {
        float p = __expf(logit[nt2][vv] - mx);
        logit[nt2][vv] = p; se += p;
      }
      #pragma unroll
      for (int off = 1; off < 16; off <<= 1) se += __shfl_xor(se, off, 64);
      float inv = 1.0f / se;
      #pragma unroll
      for (int nt2 = 0; nt2 < 7; nt2++) logit[nt2][vv] *= inv;
    }
    // PV chunked through wave-private 16x40 slot (wave-local round trip)
    f32x4 o0 = {}, o1 = {};
    #pragma unroll
    for (int ch = 0; ch < 4; ch++) {
      #pragma unroll
      for (int nl = 0; nl < 2; nl++) {
        int nt2 = ch * 2 + nl;
        #pragma unroll
        for (int vv = 0; vv < 4; vv++) {
          bf16_t pv = (nt2 < 7) ? (bf16_t)logit[nt2][vv] : (bf16_t)0.0f;
          PSc(wid, g * 4 + vv, nl * 16 + li) = pv;
        }
      }
      bf16x8 pf = *(const bf16x8*)&PSc(wid, li, g * 8);
      bf16x8 v0 = *(const bf16x8*)&VT(h * 32 + li, ch * 32 + g * 8);
      bf16x8 v1 = *(const bf16x8*)&VT(h * 32 + 16 + li, ch * 32 + g * 8);
      o0 = mfma16(pf, v0, o0);
      o1 = mfma16(pf, v1, o1);
    }
    // head output overwrites Q's (already-consumed) head-h columns
    #pragma unroll
    for (int vv = 0; vv < 4; vv++) {
      int row = mt * 16 + g * 4 + vv;
      if (row < 98) {
        QS(row, h * 32 + li)      = (bf16_t)o0[vv];
        QS(row, h * 32 + 16 + li) = (bf16_t)o1[vv];
      }
    }
  }
  __syncthreads();                       // attn-out complete (cross-wave cols)

  // ---- proj GEMM: C1 = Ao @ wp^T + pb -> Ks overlay ----
  float* bfb = qb;                        // qkv bias dead
  if (tid < 192) bfb[tid] = proj_b[tid];
  bf16x8 a2[6];
  #pragma unroll
  for (int ks = 0; ks < 6; ks++)
    a2[ks] = *(const bf16x8*)&QS(rqc, ks * 32 + g * 8);
  #pragma unroll
  for (int i = 0; i < 2; i++) {
    int c = tid + 896 * i;
    if (c < 1536) {
      int rr = c / 24, ck = c % 24;
      st[i] = *(const uint4*)(wp + (size_t)rr * 192 + ck * 8);
    }
  }
  for (int nt = 0; nt < 3; nt++) {
    __syncthreads();                      // nt=0: all PV reads of P slots done
    #pragma unroll
    for (int i = 0; i < 2; i++) {
      int c = tid + 896 * i;
      if (c < 1536) {
        int rr = c / 24, ck = c % 24;
        *(uint4*)&BS(rr, ck * 8) = st[i];
      }
    }
    __syncthreads();
    if (nt < 2) {
      #pragma unroll
      for (int i = 0; i < 2; i++) {
        int c = tid + 896 * i;
        if (c < 1536) {
          int rr = c / 24, ck = c % 24;
          st[i] = *(const uint4*)(wp + (size_t)(nt + 1) * 12288 + (size_t)rr * 192 + ck * 8);
        }
      }
    }
    f32x4 acc[2] = {};
    #pragma unroll
    for (int ks = 0; ks < 6; ks++) {
      bf16x8 a = a2[ks];
      #pragma unroll
      for (int nl = 0; nl < 2; nl++) {
        bf16x8 b = *(const bf16x8*)&BS((wn * 2 + nl) * 16 + li, ks * 32 + g * 8);
        acc[nl] = mfma16(a, b, acc[nl]);
      }
    }
    #pragma unroll
    for (int nl = 0; nl < 2; nl++)
    #pragma unroll
    for (int vv = 0; vv < 4; vv++) {
      int row = wm * 16 + g * 4 + vv;
      if (row < 98) {
        int col = nt * 64 + (wn * 2 + nl) * 16 + li;
        KS(row, col) = (bf16_t)(acc[nl][vv] + bfb[col]);
      }
    }
  }
  __syncthreads();                        // C1 complete (cross-wave cols)

  // ---- fc1 GEMM + GELU + residual ----
  if (tid < 192) bfb[tid] = fc1_b[tid];   // pb dead (last read pre-barrier)
  bf16x8 a3[6];
  #pragma unroll
  for (int ks = 0; ks < 6; ks++)
    a3[ks] = *(const bf16x8*)&KS(rqc, ks * 32 + g * 8);
  #pragma unroll
  for (int i = 0; i < 2; i++) {
    int c = tid + 896 * i;
    if (c < 1536) {
      int rr = c / 24, ck = c % 24;
      st[i] = *(const uint4*)(wf + (size_t)rr * 192 + ck * 8);
    }
  }
  size_t growv[4];
  #pragma unroll
  for (int vv = 0; vv < 4; vv++) {
    int row = wm * 16 + g * 4 + vv;
    growv[vv] = (row < 98) ? wrow_to_grow(win * 98 + row) : (size_t)0;
  }
  for (int nt = 0; nt < 3; nt++) {
    __syncthreads();
    #pragma unroll
    for (int i = 0; i < 2; i++) {
      int c = tid + 896 * i;
      if (c < 1536) {
        int rr = c / 24, ck = c % 24;
        *(uint4*)&BS(rr, ck * 8) = st[i];
      }
    }
    __syncthreads();
    if (nt < 2) {
      #pragma unroll
      for (int i = 0; i < 2; i++) {
        int c = tid + 896 * i;
        if (c < 1536) {
          int rr = c / 24, ck = c % 24;
          st[i] = *(const uint4*)(wf + (size_t)(nt + 1) * 12288 + (size_t)rr * 192 + ck * 8);
        }
      }
    }
    f32x4 acc[2] = {};
    #pragma unroll
    for (int ks = 0; ks < 6; ks++) {
      bf16x8 a = a3[ks];
      #pragma unroll
      for (int nl = 0; nl < 2; nl++) {
        bf16x8 b = *(const bf16x8*)&BS((wn * 2 + nl) * 16 + li, ks * 32 + g * 8);
        acc[nl] = mfma16(a, b, acc[nl]);
      }
    }
    #pragma unroll
    for (int vv = 0; vv < 4; vv++) {
      int row = wm * 16 + g * 4 + vv;
      if (row < 98) {
        const float* xr = x + growv[vv] * 192;
        float* op = out + growv[vv] * 192;
        #pragma unroll
        for (int nl = 0; nl < 2; nl++) {
          int col = nt * 64 + (wn * 2 + nl) * 16 + li;
          float val = acc[nl][vv] + bfb[col];
          float ge = 0.5f * val * (1.0f + erff(val * 0.70710678118654752f));
          op[col] = xr[col] + ge;
        }
      }
    }
  }
  #undef BS
  #undef PSc
  #undef QS
  #undef KS
  #undef VT
}

// ---------------- launch ----------------
extern "C" void kernel_launch(void* const* d_in, const int* in_sizes, int n_in,
                              void* d_out, int out_size, void* d_ws, size_t ws_size,
                              hipStream_t stream) {
  (void)in_sizes; (void)n_in; (void)out_size; (void)ws_size;
  const float* x         = (const float*)d_in[0];
  const float* attn_mask = (const float*)d_in[1];
  const float* n1g       = (const float*)d_in[2];
  const float* n1b       = (const float*)d_in[3];
  const float* qkv_w     = (const float*)d_in[4];
  const float* qkv_b     = (const float*)d_in[5];
  const float* rel_bias  = (const float*)d_in[6];
  const float* proj_w    = (const float*)d_in[7];
  const float* proj_b    = (const float*)d_in[8];
  const float* fc1_w     = (const float*)d_in[9];
  const float* fc1_b     = (const float*)d_in[10];
  float* out = (float*)d_out;

  char* ws = (char*)d_ws;
  size_t off = 0;
  auto alloc = [&](size_t bytes) -> char* {
    char* p = ws + off;
    off += (bytes + 255) & ~(size_t)255;
    return p;
  };
  bf16_t* wq  = (bf16_t*)alloc(110592 * 2);
  bf16_t* wp  = (bf16_t*)alloc(36864 * 2);
  bf16_t* wf  = (bf16_t*)alloc(36864 * 2);
  bf16_t* bmr = (bf16_t*)alloc((size_t)688128 * 2);

  prep_all_kernel<<<3408, 256, 0, stream>>>(qkv_w, proj_w, fc1_w, rel_bias,
                                            attn_mask, wq, wp, wf, bmr);
  fused_kernel<<<1024, 896, 0, stream>>>(x, n1g, n1b, wq, qkv_b, wp, proj_b,
                                         wf, fc1_b, bmr, out);
}